// Round 3
// baseline (874.424 us; speedup 1.0000x reference)
//
#include <hip/hip_runtime.h>
#include <hip/hip_bf16.h>
#include <math.h>

#define KC 32
#define SPLIT 8   // support-dimension split for the attention kernel (occupancy)

// ---------------------------------------------------------------------------
// Encoder GEMM: out[n][D] = X[n][K] @ W[K][D] + b, fp32, 64x64 tile, 4x4 micro
// ---------------------------------------------------------------------------
__global__ __launch_bounds__(256) void encode_gemm_kernel(
    const float* __restrict__ X, const float* __restrict__ W,
    const float* __restrict__ bias, float* __restrict__ out,
    int K, int D) {
  __shared__ float As[KC][68];  // transposed: As[k][row], pad 68 keeps float4 align + spreads banks
  __shared__ float Bs[KC][68];  // Bs[k][col]
  const int tid = threadIdx.x;
  const int tx = tid & 15, ty = tid >> 4;
  const long row0 = (long)blockIdx.x * 64, col0 = (long)blockIdx.y * 64;
  float acc[4][4] = {};
  for (int k0 = 0; k0 < K; k0 += KC) {
    // stage A tile (64 rows x KC cols), transposed into As[k][r]
#pragma unroll
    for (int i = 0; i < 2; i++) {
      int li = i * 256 + tid;          // 0..511
      int r = li >> 3, c4 = li & 7;    // 8 float4 per row
      float4 v = *(const float4*)(X + (row0 + r) * K + k0 + c4 * 4);
      As[c4 * 4 + 0][r] = v.x; As[c4 * 4 + 1][r] = v.y;
      As[c4 * 4 + 2][r] = v.z; As[c4 * 4 + 3][r] = v.w;
    }
    // stage B tile (KC rows x 64 cols)
#pragma unroll
    for (int i = 0; i < 2; i++) {
      int li = i * 256 + tid;
      int r = li >> 4, c4 = li & 15;   // 16 float4 per row
      float4 v = *(const float4*)(W + (long)(k0 + r) * D + col0 + c4 * 4);
      *(float4*)&Bs[r][c4 * 4] = v;
    }
    __syncthreads();
#pragma unroll
    for (int k = 0; k < KC; k++) {
      float4 a = *(const float4*)&As[k][ty * 4];
      float4 b = *(const float4*)&Bs[k][tx * 4];
      acc[0][0] += a.x * b.x; acc[0][1] += a.x * b.y; acc[0][2] += a.x * b.z; acc[0][3] += a.x * b.w;
      acc[1][0] += a.y * b.x; acc[1][1] += a.y * b.y; acc[1][2] += a.y * b.z; acc[1][3] += a.y * b.w;
      acc[2][0] += a.z * b.x; acc[2][1] += a.z * b.y; acc[2][2] += a.z * b.z; acc[2][3] += a.z * b.w;
      acc[3][0] += a.w * b.x; acc[3][1] += a.w * b.y; acc[3][2] += a.w * b.z; acc[3][3] += a.w * b.w;
    }
    __syncthreads();
  }
  float bl[4];
#pragma unroll
  for (int j = 0; j < 4; j++) bl[j] = bias[col0 + tx * 4 + j];
#pragma unroll
  for (int i = 0; i < 4; i++) {
    float4 o;
    o.x = acc[i][0] + bl[0]; o.y = acc[i][1] + bl[1];
    o.z = acc[i][2] + bl[2]; o.w = acc[i][3] + bl[3];
    *(float4*)(out + (row0 + ty * 4 + i) * D + col0 + tx * 4) = o;
  }
}

// ---------------------------------------------------------------------------
// In-place row L2-normalize: one wave per row (D = 512 -> 2 float4 per lane)
// ---------------------------------------------------------------------------
__global__ __launch_bounds__(256) void norm_kernel(float* __restrict__ emb, int nrows, int D) {
  int row = (int)((blockIdx.x * blockDim.x + threadIdx.x) >> 6);
  int lane = threadIdx.x & 63;
  if (row >= nrows) return;
  float4* p = (float4*)(emb + (size_t)row * D);
  float4 v0 = p[lane];
  float4 v1 = p[lane + 64];
  float ss = v0.x * v0.x + v0.y * v0.y + v0.z * v0.z + v0.w * v0.w
           + v1.x * v1.x + v1.y * v1.y + v1.z * v1.z + v1.w * v1.w;
#pragma unroll
  for (int off = 32; off > 0; off >>= 1) ss += __shfl_xor(ss, off);
  float inv = 1.0f / fmaxf(sqrtf(ss), 1e-12f);
  v0.x *= inv; v0.y *= inv; v0.z *= inv; v0.w *= inv;
  v1.x *= inv; v1.y *= inv; v1.z *= inv; v1.w *= inv;
  p[lane] = v0;
  p[lane + 64] = v1;
}

// ---------------------------------------------------------------------------
// Fused attention: per 64-query tile x support-slice, compute scores (GEMM),
// exp, accumulate into 64-class buckets in LDS (scores bounded in [-1,1] so
// softmax needs no max subtraction). Writes per-split partial buckets.
// ---------------------------------------------------------------------------
__global__ __launch_bounds__(256) void attn_kernel(
    const float* __restrict__ Q, const float* __restrict__ S,
    const int* __restrict__ labels, float* __restrict__ partial,
    int nq, int ns_part, int D) {
  __shared__ float Qs[KC][68];
  __shared__ float Ss[KC][68];
  __shared__ float buckets[64][65];  // pad 65: bank = (q + lab) % 32
  __shared__ int lab[64];
  const int tid = threadIdx.x;
  const int tx = tid & 15, ty = tid >> 4;
  const long q0 = (long)blockIdx.x * 64;
  const int part = blockIdx.y;
  const int s_begin = part * ns_part;

  for (int i = tid; i < 64 * 65; i += 256) ((float*)buckets)[i] = 0.0f;
  __syncthreads();

  for (int st = 0; st < ns_part; st += 64) {
    const long s0 = s_begin + st;
    if (tid < 64) lab[tid] = labels[s0 + tid];
    float acc[4][4] = {};
    for (int k0 = 0; k0 < D; k0 += KC) {
      // stage Q chunk transposed
#pragma unroll
      for (int i = 0; i < 2; i++) {
        int li = i * 256 + tid;
        int r = li >> 3, c4 = li & 7;
        float4 v = *(const float4*)(Q + (q0 + r) * D + k0 + c4 * 4);
        Qs[c4 * 4 + 0][r] = v.x; Qs[c4 * 4 + 1][r] = v.y;
        Qs[c4 * 4 + 2][r] = v.z; Qs[c4 * 4 + 3][r] = v.w;
      }
      // stage S chunk transposed (B operand = s_emb rows as columns)
#pragma unroll
      for (int i = 0; i < 2; i++) {
        int li = i * 256 + tid;
        int r = li >> 3, c4 = li & 7;
        float4 v = *(const float4*)(S + (s0 + r) * D + k0 + c4 * 4);
        Ss[c4 * 4 + 0][r] = v.x; Ss[c4 * 4 + 1][r] = v.y;
        Ss[c4 * 4 + 2][r] = v.z; Ss[c4 * 4 + 3][r] = v.w;
      }
      __syncthreads();
#pragma unroll
      for (int k = 0; k < KC; k++) {
        float4 a = *(const float4*)&Qs[k][ty * 4];
        float4 b = *(const float4*)&Ss[k][tx * 4];
        acc[0][0] += a.x * b.x; acc[0][1] += a.x * b.y; acc[0][2] += a.x * b.z; acc[0][3] += a.x * b.w;
        acc[1][0] += a.y * b.x; acc[1][1] += a.y * b.y; acc[1][2] += a.y * b.z; acc[1][3] += a.y * b.w;
        acc[2][0] += a.z * b.x; acc[2][1] += a.z * b.y; acc[2][2] += a.z * b.z; acc[2][3] += a.z * b.w;
        acc[3][0] += a.w * b.x; acc[3][1] += a.w * b.y; acc[3][2] += a.w * b.z; acc[3][3] += a.w * b.w;
      }
      __syncthreads();
    }
    // exp + bucket accumulate (scores in [-1,1], exp is safe)
#pragma unroll
    for (int i = 0; i < 4; i++) {
#pragma unroll
      for (int j = 0; j < 4; j++) {
        float e = expf(acc[i][j]);
        atomicAdd(&buckets[ty * 4 + i][lab[tx * 4 + j]], e);
      }
    }
    __syncthreads();  // atomics done before next tile's lab overwrite
  }
  // write partial buckets for this (q-tile, support-part)
  for (int i = tid; i < 64 * 64; i += 256) {
    int q = i >> 6, c = i & 63;
    partial[((size_t)part * nq + (q0 + q)) * 64 + c] = buckets[q][c];
  }
}

// ---------------------------------------------------------------------------
// Combine: sum partials over splits; softmax denominator = row-sum of buckets
// ---------------------------------------------------------------------------
__global__ __launch_bounds__(256) void combine_kernel(
    const float* __restrict__ partial, float* __restrict__ out, int nq) {
  int q = (int)((blockIdx.x * blockDim.x + threadIdx.x) >> 6);
  int lane = threadIdx.x & 63;
  if (q >= nq) return;
  float v = 0.0f;
#pragma unroll
  for (int h = 0; h < SPLIT; h++)
    v += partial[((size_t)h * nq + q) * 64 + lane];
  float s = v;
#pragma unroll
  for (int off = 32; off > 0; off >>= 1) s += __shfl_xor(s, off);
  out[(size_t)q * 64 + lane] = v / s;
}

// ---------------------------------------------------------------------------
extern "C" void kernel_launch(void* const* d_in, const int* in_sizes, int n_in,
                              void* d_out, int out_size, void* d_ws, size_t ws_size,
                              hipStream_t stream) {
  const float* support = (const float*)d_in[0];
  const float* query   = (const float*)d_in[1];
  const float* W       = (const float*)d_in[2];
  const float* b       = (const float*)d_in[3];
  const int*   labels  = (const int*)d_in[4];

  const int d_dim    = in_sizes[3];            // 512
  const int in_dim   = in_sizes[2] / d_dim;    // 1024
  const int n_support = in_sizes[0] / in_dim;  // 4096
  const int n_query   = in_sizes[1] / in_dim;  // 8192

  float* s_emb   = (float*)d_ws;
  float* q_emb   = s_emb + (size_t)n_support * d_dim;
  float* partial = q_emb + (size_t)n_query * d_dim;  // SPLIT * n_query * 64

  dim3 blk(256);
  encode_gemm_kernel<<<dim3(n_support / 64, d_dim / 64), blk, 0, stream>>>(
      support, W, b, s_emb, in_dim, d_dim);
  encode_gemm_kernel<<<dim3(n_query / 64, d_dim / 64), blk, 0, stream>>>(
      query, W, b, q_emb, in_dim, d_dim);
  norm_kernel<<<dim3(n_support / 4), blk, 0, stream>>>(s_emb, n_support, d_dim);
  norm_kernel<<<dim3(n_query / 4), blk, 0, stream>>>(q_emb, n_query, d_dim);
  attn_kernel<<<dim3(n_query / 64, SPLIT), blk, 0, stream>>>(
      q_emb, s_emb, labels, partial, n_query, n_support / SPLIT, d_dim);
  combine_kernel<<<dim3(n_query / 4), blk, 0, stream>>>(partial, (float*)d_out, n_query);
}

// Round 4
// 487.836 us; speedup vs baseline: 1.7925x; 1.7925x over previous
//
#include <hip/hip_runtime.h>
#include <hip/hip_bf16.h>
#include <math.h>

#define KC 32
#define SPLIT 8   // support-dimension split for the attention kernel

typedef __attribute__((ext_vector_type(8))) short bf16x8;  // MFMA A/B frag (4 VGPR)
typedef __attribute__((ext_vector_type(4))) float f32x4;   // MFMA C/D frag

static __device__ inline ushort f2bf(float x) {
  __hip_bfloat16 h = __float2bfloat16(x);
  return *reinterpret_cast<ushort*>(&h);
}

// ---------------------------------------------------------------------------
// Encoder GEMM: out[n][D] = X[n][K] @ W[K][D] + b, fp32 (kept fp32 this round;
// only 12.9 GF total — isolates bf16 numeric risk to the score GEMM)
// ---------------------------------------------------------------------------
__global__ __launch_bounds__(256) void encode_gemm_kernel(
    const float* __restrict__ X, const float* __restrict__ W,
    const float* __restrict__ bias, float* __restrict__ out,
    int K, int D) {
  __shared__ float As[KC][68];
  __shared__ float Bs[KC][68];
  const int tid = threadIdx.x;
  const int tx = tid & 15, ty = tid >> 4;
  const long row0 = (long)blockIdx.x * 64, col0 = (long)blockIdx.y * 64;
  float acc[4][4] = {};
  for (int k0 = 0; k0 < K; k0 += KC) {
#pragma unroll
    for (int i = 0; i < 2; i++) {
      int li = i * 256 + tid;
      int r = li >> 3, c4 = li & 7;
      float4 v = *(const float4*)(X + (row0 + r) * K + k0 + c4 * 4);
      As[c4 * 4 + 0][r] = v.x; As[c4 * 4 + 1][r] = v.y;
      As[c4 * 4 + 2][r] = v.z; As[c4 * 4 + 3][r] = v.w;
    }
#pragma unroll
    for (int i = 0; i < 2; i++) {
      int li = i * 256 + tid;
      int r = li >> 4, c4 = li & 15;
      float4 v = *(const float4*)(W + (long)(k0 + r) * D + col0 + c4 * 4);
      *(float4*)&Bs[r][c4 * 4] = v;
    }
    __syncthreads();
#pragma unroll
    for (int k = 0; k < KC; k++) {
      float4 a = *(const float4*)&As[k][ty * 4];
      float4 b = *(const float4*)&Bs[k][tx * 4];
      acc[0][0] += a.x * b.x; acc[0][1] += a.x * b.y; acc[0][2] += a.x * b.z; acc[0][3] += a.x * b.w;
      acc[1][0] += a.y * b.x; acc[1][1] += a.y * b.y; acc[1][2] += a.y * b.z; acc[1][3] += a.y * b.w;
      acc[2][0] += a.z * b.x; acc[2][1] += a.z * b.y; acc[2][2] += a.z * b.z; acc[2][3] += a.z * b.w;
      acc[3][0] += a.w * b.x; acc[3][1] += a.w * b.y; acc[3][2] += a.w * b.z; acc[3][3] += a.w * b.w;
    }
    __syncthreads();
  }
  float bl[4];
#pragma unroll
  for (int j = 0; j < 4; j++) bl[j] = bias[col0 + tx * 4 + j];
#pragma unroll
  for (int i = 0; i < 4; i++) {
    float4 o;
    o.x = acc[i][0] + bl[0]; o.y = acc[i][1] + bl[1];
    o.z = acc[i][2] + bl[2]; o.w = acc[i][3] + bl[3];
    *(float4*)(out + (row0 + ty * 4 + i) * D + col0 + tx * 4) = o;
  }
}

// ---------------------------------------------------------------------------
// Row L2-normalize fp32 -> bf16 (one wave per row, D = 512)
// ---------------------------------------------------------------------------
__global__ __launch_bounds__(256) void norm_bf16_kernel(
    const float* __restrict__ in, ushort* __restrict__ outb, int nrows, int D) {
  int row = (int)((blockIdx.x * blockDim.x + threadIdx.x) >> 6);
  int lane = threadIdx.x & 63;
  if (row >= nrows) return;
  const float4* p = (const float4*)(in + (size_t)row * D);
  float4 v0 = p[lane];
  float4 v1 = p[lane + 64];
  float ss = v0.x * v0.x + v0.y * v0.y + v0.z * v0.z + v0.w * v0.w
           + v1.x * v1.x + v1.y * v1.y + v1.z * v1.z + v1.w * v1.w;
#pragma unroll
  for (int off = 32; off > 0; off >>= 1) ss += __shfl_xor(ss, off);
  float inv = 1.0f / fmaxf(sqrtf(ss), 1e-12f);
  ushort4 u0, u1;
  u0.x = f2bf(v0.x * inv); u0.y = f2bf(v0.y * inv);
  u0.z = f2bf(v0.z * inv); u0.w = f2bf(v0.w * inv);
  u1.x = f2bf(v1.x * inv); u1.y = f2bf(v1.y * inv);
  u1.z = f2bf(v1.z * inv); u1.w = f2bf(v1.w * inv);
  ushort* o = outb + (size_t)row * D;
  *(ushort4*)(o + 4 * lane) = u0;
  *(ushort4*)(o + 256 + 4 * lane) = u1;
}

// ---------------------------------------------------------------------------
// MFMA attention: 64-query block x support slice. Scores via 16x16x32 bf16
// MFMA (A=Q frag hoisted in regs, B=S frag direct from global/L2 — S is 4MB,
// L2-resident; both frags are 16B-contiguous row-major reads). Then exp +
// LDS-atomic bucket accumulate (scores in [-1,1] -> no max subtraction).
// A-frag layout: row=lane&15, k=(lane>>4)*8+j. C/D: col=lane&15,
// row=(lane>>4)*4+reg  [learn_hip m89 verified].
// ---------------------------------------------------------------------------
__global__ __launch_bounds__(256) void attn_mfma_kernel(
    const ushort* __restrict__ Qb, const ushort* __restrict__ Sb,
    const int* __restrict__ labels, float* __restrict__ partial,
    int nq, int ns_part, int D) {
  __shared__ float buckets[64][65];  // pad 65 spreads (row,label) across banks
  __shared__ int lab[64];
  const int tid = threadIdx.x;
  const int wave = tid >> 6, lane = tid & 63;
  const int fr = lane & 15, kg = lane >> 4;
  const long q0 = (long)blockIdx.x * 64;
  const int part = blockIdx.y;
  const long s_begin = (long)part * ns_part;

  for (int i = tid; i < 64 * 65; i += 256) ((float*)buckets)[i] = 0.0f;

  // Q-hoist: wave owns queries [q0 + wave*16, +16); 16 K-steps of bf16x8
  bf16x8 qf[16];
  const ushort* qrow = Qb + (q0 + wave * 16 + fr) * (size_t)D;
#pragma unroll
  for (int t = 0; t < 16; t++)
    qf[t] = *(const bf16x8*)(qrow + t * 32 + kg * 8);

  for (int st = 0; st < ns_part; st += 64) {
    const long s0 = s_begin + st;
    __syncthreads();               // prev-iter atomics complete (covers bucket zeroing too)
    if (tid < 64) lab[tid] = labels[s0 + tid];
    __syncthreads();               // lab visible
    f32x4 acc[4];
#pragma unroll
    for (int c = 0; c < 4; c++) acc[c] = (f32x4){0.f, 0.f, 0.f, 0.f};
#pragma unroll
    for (int t = 0; t < 16; t++) {
#pragma unroll
      for (int c = 0; c < 4; c++) {
        const ushort* srow = Sb + (s0 + c * 16 + fr) * (size_t)D;
        bf16x8 bfr = *(const bf16x8*)(srow + t * 32 + kg * 8);
        acc[c] = __builtin_amdgcn_mfma_f32_16x16x32_bf16(qf[t], bfr, acc[c], 0, 0, 0);
      }
    }
    // exp + bucket: lane's acc[c][r] = score(query q0+wave*16+kg*4+r,
    //                                        support s0+c*16+fr)
#pragma unroll
    for (int c = 0; c < 4; c++) {
      int lb = lab[c * 16 + fr];
#pragma unroll
      for (int r = 0; r < 4; r++) {
        float e = __expf(acc[c][r]);
        atomicAdd(&buckets[wave * 16 + kg * 4 + r][lb], e);
      }
    }
  }
  __syncthreads();
  for (int i = tid; i < 64 * 64; i += 256) {
    int q = i >> 6, c = i & 63;
    partial[((size_t)part * nq + (q0 + q)) * 64 + c] = buckets[q][c];
  }
}

// ---------------------------------------------------------------------------
// Combine: sum partials over splits; denominator = row-sum of buckets
// ---------------------------------------------------------------------------
__global__ __launch_bounds__(256) void combine_kernel(
    const float* __restrict__ partial, float* __restrict__ out, int nq) {
  int q = (int)((blockIdx.x * blockDim.x + threadIdx.x) >> 6);
  int lane = threadIdx.x & 63;
  if (q >= nq) return;
  float v = 0.0f;
#pragma unroll
  for (int h = 0; h < SPLIT; h++)
    v += partial[((size_t)h * nq + q) * 64 + lane];
  float s = v;
#pragma unroll
  for (int off = 32; off > 0; off >>= 1) s += __shfl_xor(s, off);
  out[(size_t)q * 64 + lane] = v / s;
}

// ---------------------------------------------------------------------------
extern "C" void kernel_launch(void* const* d_in, const int* in_sizes, int n_in,
                              void* d_out, int out_size, void* d_ws, size_t ws_size,
                              hipStream_t stream) {
  const float* support = (const float*)d_in[0];
  const float* query   = (const float*)d_in[1];
  const float* W       = (const float*)d_in[2];
  const float* b       = (const float*)d_in[3];
  const int*   labels  = (const int*)d_in[4];

  const int d_dim    = in_sizes[3];            // 512
  const int in_dim   = in_sizes[2] / d_dim;    // 1024
  const int n_support = in_sizes[0] / in_dim;  // 4096
  const int n_query   = in_sizes[1] / in_dim;  // 8192

  float*  s_emb = (float*)d_ws;                               // 4096*512 f32
  float*  q_emb = s_emb + (size_t)n_support * d_dim;          // 8192*512 f32
  ushort* s_bf  = (ushort*)(q_emb + (size_t)n_query * d_dim); // 4096*512 bf16
  ushort* q_bf  = s_bf + (size_t)n_support * d_dim;           // 8192*512 bf16
  float*  partial = (float*)(q_bf + (size_t)n_query * d_dim); // SPLIT*8192*64 f32

  dim3 blk(256);
  encode_gemm_kernel<<<dim3(n_support / 64, d_dim / 64), blk, 0, stream>>>(
      support, W, b, s_emb, in_dim, d_dim);
  encode_gemm_kernel<<<dim3(n_query / 64, d_dim / 64), blk, 0, stream>>>(
      query, W, b, q_emb, in_dim, d_dim);
  norm_bf16_kernel<<<dim3(n_support / 4), blk, 0, stream>>>(s_emb, s_bf, n_support, d_dim);
  norm_bf16_kernel<<<dim3(n_query / 4), blk, 0, stream>>>(q_emb, q_bf, n_query, d_dim);
  attn_mfma_kernel<<<dim3(n_query / 64, SPLIT), blk, 0, stream>>>(
      q_bf, s_bf, labels, partial, n_query, n_support / SPLIT, d_dim);
  combine_kernel<<<dim3(n_query / 4), blk, 0, stream>>>(partial, (float*)d_out, n_query);
}

// Round 5
// 445.887 us; speedup vs baseline: 1.9611x; 1.0941x over previous
//
#include <hip/hip_runtime.h>
#include <hip/hip_bf16.h>
#include <math.h>

#define SPLIT 16  // support-dimension split for the attention kernel (8 blk/CU)

typedef __attribute__((ext_vector_type(8))) short bf16x8;  // MFMA A/B frag (4 VGPR)
typedef __attribute__((ext_vector_type(4))) float f32x4;   // MFMA C/D frag

static __device__ inline ushort f2bf(float x) {
  __hip_bfloat16 h = __float2bfloat16(x);
  return *reinterpret_cast<ushort*>(&h);
}

// ---------------------------------------------------------------------------
// Elementwise cast f32 -> bf16 (n multiple of 4)
// ---------------------------------------------------------------------------
__global__ __launch_bounds__(256) void cast_bf16_kernel(
    const float* __restrict__ in, ushort* __restrict__ out, size_t n4) {
  size_t i = (size_t)blockIdx.x * blockDim.x + threadIdx.x;
  size_t stride = (size_t)gridDim.x * blockDim.x;
  for (; i < n4; i += stride) {
    float4 v = ((const float4*)in)[i];
    ushort4 u;
    u.x = f2bf(v.x); u.y = f2bf(v.y); u.z = f2bf(v.z); u.w = f2bf(v.w);
    ((ushort4*)out)[i] = u;
  }
}

// ---------------------------------------------------------------------------
// Transpose-cast W[K][D] f32 -> Wt[D][K] bf16 (64x64 LDS tiles)
// ---------------------------------------------------------------------------
__global__ __launch_bounds__(256) void transpose_cast_kernel(
    const float* __restrict__ W, ushort* __restrict__ Wt, int K, int D) {
  __shared__ float t[64][65];
  const int k0 = blockIdx.x * 64, d0 = blockIdx.y * 64;
  const int r = threadIdx.x >> 6, c = threadIdx.x & 63;
#pragma unroll
  for (int i = 0; i < 16; i++)
    t[r + i * 4][c] = W[(size_t)(k0 + r + i * 4) * D + d0 + c];
  __syncthreads();
#pragma unroll
  for (int i = 0; i < 16; i++)
    Wt[(size_t)(d0 + r + i * 4) * K + k0 + c] = f2bf(t[c][r + i * 4]);
}

// ---------------------------------------------------------------------------
// Encoder MFMA GEMM: emb[n][D] = Xb[n][K] @ Wt[D][K]^T + b  (bf16 in, f32 out)
// Same fragment pattern as attn (verified): A row=lane&15, k=(lane>>4)*8+j;
// C/D col=lane&15, row=(lane>>4)*4+reg.
// ---------------------------------------------------------------------------
__global__ __launch_bounds__(256) void encode_mfma_kernel(
    const ushort* __restrict__ Xb, const ushort* __restrict__ Wt,
    const float* __restrict__ bias, float* __restrict__ emb,
    int K, int D) {
  const int tid = threadIdx.x;
  const int wave = tid >> 6, lane = tid & 63;
  const int fr = lane & 15, kg = lane >> 4;
  const long row0 = (long)blockIdx.x * 64, col0 = (long)blockIdx.y * 64;

  f32x4 acc[4];
#pragma unroll
  for (int c = 0; c < 4; c++) acc[c] = (f32x4){0.f, 0.f, 0.f, 0.f};

  const ushort* xrow = Xb + (row0 + wave * 16 + fr) * (size_t)K;
  const int nt = K / 32;
  for (int t = 0; t < nt; t++) {
    bf16x8 af = *(const bf16x8*)(xrow + t * 32 + kg * 8);
#pragma unroll
    for (int c = 0; c < 4; c++) {
      const ushort* wrow = Wt + (col0 + c * 16 + fr) * (size_t)K;
      bf16x8 bf = *(const bf16x8*)(wrow + t * 32 + kg * 8);
      acc[c] = __builtin_amdgcn_mfma_f32_16x16x32_bf16(af, bf, acc[c], 0, 0, 0);
    }
  }
#pragma unroll
  for (int c = 0; c < 4; c++) {
    float bl = bias[col0 + c * 16 + fr];
#pragma unroll
    for (int r = 0; r < 4; r++)
      emb[(row0 + wave * 16 + kg * 4 + r) * (size_t)D + col0 + c * 16 + fr] =
          acc[c][r] + bl;
  }
}

// ---------------------------------------------------------------------------
// Row L2-normalize fp32 -> bf16 (one wave per row, D = 512)
// ---------------------------------------------------------------------------
__global__ __launch_bounds__(256) void norm_bf16_kernel(
    const float* __restrict__ in, ushort* __restrict__ outb, int nrows, int D) {
  int row = (int)((blockIdx.x * blockDim.x + threadIdx.x) >> 6);
  int lane = threadIdx.x & 63;
  if (row >= nrows) return;
  const float4* p = (const float4*)(in + (size_t)row * D);
  float4 v0 = p[lane];
  float4 v1 = p[lane + 64];
  float ss = v0.x * v0.x + v0.y * v0.y + v0.z * v0.z + v0.w * v0.w
           + v1.x * v1.x + v1.y * v1.y + v1.z * v1.z + v1.w * v1.w;
#pragma unroll
  for (int off = 32; off > 0; off >>= 1) ss += __shfl_xor(ss, off);
  float inv = 1.0f / fmaxf(sqrtf(ss), 1e-12f);
  ushort4 u0, u1;
  u0.x = f2bf(v0.x * inv); u0.y = f2bf(v0.y * inv);
  u0.z = f2bf(v0.z * inv); u0.w = f2bf(v0.w * inv);
  u1.x = f2bf(v1.x * inv); u1.y = f2bf(v1.y * inv);
  u1.z = f2bf(v1.z * inv); u1.w = f2bf(v1.w * inv);
  ushort* o = outb + (size_t)row * D;
  *(ushort4*)(o + 4 * lane) = u0;
  *(ushort4*)(o + 256 + 4 * lane) = u1;
}

// ---------------------------------------------------------------------------
// MFMA attention (unchanged body from round 4; SPLIT now 16 for occupancy):
// scores via 16x16x32 bf16 MFMA, exp + LDS-atomic 64-class bucket accumulate.
// ---------------------------------------------------------------------------
__global__ __launch_bounds__(256) void attn_mfma_kernel(
    const ushort* __restrict__ Qb, const ushort* __restrict__ Sb,
    const int* __restrict__ labels, float* __restrict__ partial,
    int nq, int ns_part, int D) {
  __shared__ float buckets[64][65];
  __shared__ int lab[64];
  const int tid = threadIdx.x;
  const int wave = tid >> 6, lane = tid & 63;
  const int fr = lane & 15, kg = lane >> 4;
  const long q0 = (long)blockIdx.x * 64;
  const int part = blockIdx.y;
  const long s_begin = (long)part * ns_part;

  for (int i = tid; i < 64 * 65; i += 256) ((float*)buckets)[i] = 0.0f;

  // Q-hoist: wave owns queries [q0 + wave*16, +16); 16 K-steps of bf16x8
  bf16x8 qf[16];
  const ushort* qrow = Qb + (q0 + wave * 16 + fr) * (size_t)D;
#pragma unroll
  for (int t = 0; t < 16; t++)
    qf[t] = *(const bf16x8*)(qrow + t * 32 + kg * 8);

  for (int st = 0; st < ns_part; st += 64) {
    const long s0 = s_begin + st;
    __syncthreads();               // prev-iter atomics complete (covers zeroing)
    if (tid < 64) lab[tid] = labels[s0 + tid];
    __syncthreads();               // lab visible
    f32x4 acc[4];
#pragma unroll
    for (int c = 0; c < 4; c++) acc[c] = (f32x4){0.f, 0.f, 0.f, 0.f};
#pragma unroll
    for (int t = 0; t < 16; t++) {
#pragma unroll
      for (int c = 0; c < 4; c++) {
        const ushort* srow = Sb + (s0 + c * 16 + fr) * (size_t)D;
        bf16x8 bfr = *(const bf16x8*)(srow + t * 32 + kg * 8);
        acc[c] = __builtin_amdgcn_mfma_f32_16x16x32_bf16(qf[t], bfr, acc[c], 0, 0, 0);
      }
    }
#pragma unroll
    for (int c = 0; c < 4; c++) {
      int lb = lab[c * 16 + fr];
#pragma unroll
      for (int r = 0; r < 4; r++) {
        float e = __expf(acc[c][r]);
        atomicAdd(&buckets[wave * 16 + kg * 4 + r][lb], e);
      }
    }
  }
  __syncthreads();
  for (int i = tid; i < 64 * 64; i += 256) {
    int q = i >> 6, c = i & 63;
    partial[((size_t)part * nq + (q0 + q)) * 64 + c] = buckets[q][c];
  }
}

// ---------------------------------------------------------------------------
// Combine: sum partials over splits; denominator = row-sum of buckets
// ---------------------------------------------------------------------------
__global__ __launch_bounds__(256) void combine_kernel(
    const float* __restrict__ partial, float* __restrict__ out, int nq, int nsplit) {
  int q = (int)((blockIdx.x * blockDim.x + threadIdx.x) >> 6);
  int lane = threadIdx.x & 63;
  if (q >= nq) return;
  float v = 0.0f;
  for (int h = 0; h < nsplit; h++)
    v += partial[((size_t)h * nq + q) * 64 + lane];
  float s = v;
#pragma unroll
  for (int off = 32; off > 0; off >>= 1) s += __shfl_xor(s, off);
  out[(size_t)q * 64 + lane] = v / s;
}

// ---------------------------------------------------------------------------
// Workspace layout (peak 49 MB, < proven 52 MB):
//  [0,24M)  Xb_s(8M)+Xb_q(16M)   -- dead after encode; reused:
//  [0,4M)   s_bf   [4M,12M) q_bf   [12M,44M) partial (32M)
//  [24M,25M) Wt     [25M,33M) s_emb  [33M,49M) q_emb
// ---------------------------------------------------------------------------
extern "C" void kernel_launch(void* const* d_in, const int* in_sizes, int n_in,
                              void* d_out, int out_size, void* d_ws, size_t ws_size,
                              hipStream_t stream) {
  const float* support = (const float*)d_in[0];
  const float* query   = (const float*)d_in[1];
  const float* W       = (const float*)d_in[2];
  const float* b       = (const float*)d_in[3];
  const int*   labels  = (const int*)d_in[4];

  const int d_dim    = in_sizes[3];            // 512
  const int in_dim   = in_sizes[2] / d_dim;    // 1024
  const int n_support = in_sizes[0] / in_dim;  // 4096
  const int n_query   = in_sizes[1] / in_dim;  // 8192

  char* base = (char*)d_ws;
  ushort* xb_s  = (ushort*)(base);
  ushort* xb_q  = (ushort*)(base + ((size_t)8 << 20));
  ushort* Wt    = (ushort*)(base + ((size_t)24 << 20));
  float*  s_emb = (float*)(base + ((size_t)25 << 20));
  float*  q_emb = (float*)(base + ((size_t)33 << 20));
  ushort* s_bf  = (ushort*)(base);                        // alias Xb_s (dead)
  ushort* q_bf  = (ushort*)(base + ((size_t)4 << 20));    // alias Xb (dead)
  float*  partial = (float*)(base + ((size_t)12 << 20));  // alias Xb/Wt/emb (dead)

  dim3 blk(256);
  cast_bf16_kernel<<<2048, blk, 0, stream>>>(support, xb_s, (size_t)n_support * in_dim / 4);
  cast_bf16_kernel<<<2048, blk, 0, stream>>>(query, xb_q, (size_t)n_query * in_dim / 4);
  transpose_cast_kernel<<<dim3(in_dim / 64, d_dim / 64), blk, 0, stream>>>(W, Wt, in_dim, d_dim);
  encode_mfma_kernel<<<dim3(n_support / 64, d_dim / 64), blk, 0, stream>>>(
      xb_s, Wt, b, s_emb, in_dim, d_dim);
  encode_mfma_kernel<<<dim3(n_query / 64, d_dim / 64), blk, 0, stream>>>(
      xb_q, Wt, b, q_emb, in_dim, d_dim);
  norm_bf16_kernel<<<dim3(n_support / 4), blk, 0, stream>>>(s_emb, s_bf, n_support, d_dim);
  norm_bf16_kernel<<<dim3(n_query / 4), blk, 0, stream>>>(q_emb, q_bf, n_query, d_dim);
  attn_mfma_kernel<<<dim3(n_query / 64, SPLIT), blk, 0, stream>>>(
      q_bf, s_bf, labels, partial, n_query, n_support / SPLIT, d_dim);
  combine_kernel<<<dim3(n_query / 4), blk, 0, stream>>>(partial, (float*)d_out, n_query, SPLIT);
}

// Round 6
// 366.023 us; speedup vs baseline: 2.3890x; 1.2182x over previous
//
#include <hip/hip_runtime.h>
#include <hip/hip_bf16.h>
#include <math.h>

#define SPLIT 8   // support split: 128x8 = 1024 blocks = 4/CU (LDS-capped at 4)

typedef __attribute__((ext_vector_type(8))) short bf16x8;  // MFMA A/B frag (4 VGPR)
typedef __attribute__((ext_vector_type(4))) float f32x4;   // MFMA C/D frag

static __device__ inline ushort f2bf(float x) {
  __hip_bfloat16 h = __float2bfloat16(x);
  return *reinterpret_cast<ushort*>(&h);
}

// ---------------------------------------------------------------------------
// Elementwise cast f32 -> bf16 (n multiple of 4)
// ---------------------------------------------------------------------------
__global__ __launch_bounds__(256) void cast_bf16_kernel(
    const float* __restrict__ in, ushort* __restrict__ out, size_t n4) {
  size_t i = (size_t)blockIdx.x * blockDim.x + threadIdx.x;
  size_t stride = (size_t)gridDim.x * blockDim.x;
  for (; i < n4; i += stride) {
    float4 v = ((const float4*)in)[i];
    ushort4 u;
    u.x = f2bf(v.x); u.y = f2bf(v.y); u.z = f2bf(v.z); u.w = f2bf(v.w);
    ((ushort4*)out)[i] = u;
  }
}

// ---------------------------------------------------------------------------
// Transpose-cast W[K][D] f32 -> Wt[D][K] bf16 (64x64 LDS tiles)
// ---------------------------------------------------------------------------
__global__ __launch_bounds__(256) void transpose_cast_kernel(
    const float* __restrict__ W, ushort* __restrict__ Wt, int K, int D) {
  __shared__ float t[64][65];
  const int k0 = blockIdx.x * 64, d0 = blockIdx.y * 64;
  const int r = threadIdx.x >> 6, c = threadIdx.x & 63;
#pragma unroll
  for (int i = 0; i < 16; i++)
    t[r + i * 4][c] = W[(size_t)(k0 + r + i * 4) * D + d0 + c];
  __syncthreads();
#pragma unroll
  for (int i = 0; i < 16; i++)
    Wt[(size_t)(d0 + r + i * 4) * K + k0 + c] = f2bf(t[c][r + i * 4]);
}

// ---------------------------------------------------------------------------
// Encoder MFMA GEMM (unchanged this round): emb = Xb @ Wt^T + b
// ---------------------------------------------------------------------------
__global__ __launch_bounds__(256) void encode_mfma_kernel(
    const ushort* __restrict__ Xb, const ushort* __restrict__ Wt,
    const float* __restrict__ bias, float* __restrict__ emb,
    int K, int D) {
  const int tid = threadIdx.x;
  const int wave = tid >> 6, lane = tid & 63;
  const int fr = lane & 15, kg = lane >> 4;
  const long row0 = (long)blockIdx.x * 64, col0 = (long)blockIdx.y * 64;

  f32x4 acc[4];
#pragma unroll
  for (int c = 0; c < 4; c++) acc[c] = (f32x4){0.f, 0.f, 0.f, 0.f};

  const ushort* xrow = Xb + (row0 + wave * 16 + fr) * (size_t)K;
  const int nt = K / 32;
  for (int t = 0; t < nt; t++) {
    bf16x8 af = *(const bf16x8*)(xrow + t * 32 + kg * 8);
#pragma unroll
    for (int c = 0; c < 4; c++) {
      const ushort* wrow = Wt + (col0 + c * 16 + fr) * (size_t)K;
      bf16x8 bf = *(const bf16x8*)(wrow + t * 32 + kg * 8);
      acc[c] = __builtin_amdgcn_mfma_f32_16x16x32_bf16(af, bf, acc[c], 0, 0, 0);
    }
  }
#pragma unroll
  for (int c = 0; c < 4; c++) {
    float bl = bias[col0 + c * 16 + fr];
#pragma unroll
    for (int r = 0; r < 4; r++)
      emb[(row0 + wave * 16 + kg * 4 + r) * (size_t)D + col0 + c * 16 + fr] =
          acc[c][r] + bl;
  }
}

// ---------------------------------------------------------------------------
// Row L2-normalize fp32 -> bf16 (one wave per row, D = 512)
// ---------------------------------------------------------------------------
__global__ __launch_bounds__(256) void norm_bf16_kernel(
    const float* __restrict__ in, ushort* __restrict__ outb, int nrows, int D) {
  int row = (int)((blockIdx.x * blockDim.x + threadIdx.x) >> 6);
  int lane = threadIdx.x & 63;
  if (row >= nrows) return;
  const float4* p = (const float4*)(in + (size_t)row * D);
  float4 v0 = p[lane];
  float4 v1 = p[lane + 64];
  float ss = v0.x * v0.x + v0.y * v0.y + v0.z * v0.z + v0.w * v0.w
           + v1.x * v1.x + v1.y * v1.y + v1.z * v1.z + v1.w * v1.w;
#pragma unroll
  for (int off = 32; off > 0; off >>= 1) ss += __shfl_xor(ss, off);
  float inv = 1.0f / fmaxf(sqrtf(ss), 1e-12f);
  ushort4 u0, u1;
  u0.x = f2bf(v0.x * inv); u0.y = f2bf(v0.y * inv);
  u0.z = f2bf(v0.z * inv); u0.w = f2bf(v0.w * inv);
  u1.x = f2bf(v1.x * inv); u1.y = f2bf(v1.y * inv);
  u1.z = f2bf(v1.z * inv); u1.w = f2bf(v1.w * inv);
  ushort* o = outb + (size_t)row * D;
  *(ushort4*)(o + 4 * lane) = u0;
  *(ushort4*)(o + 256 + 4 * lane) = u1;
}

// ---------------------------------------------------------------------------
// MFMA attention with LDS-staged S-tiles in FRAGMENT ORDER.
// Per s-tile (64 support rows) we stage K in 4 chunks of 128 (BK=128):
// LDS layout: 16 blocks btc=(tt*4+c) of 64 slots x 16B; slot l of block btc
// holds S[s0 + c*16 + (l&15)][kc*128 + tt*32 + (l>>4)*8 .. +8]  -- exactly
// lane l's B-fragment for (k-step tt, support-group c). global_load_lds
// writes linearly (base + lane*16) while each lane's GLOBAL address is the
// permuted fragment source (rule #21 pattern). ds_read_b128 is then 1024
// contiguous bytes per wave -> conflict-free.
// ---------------------------------------------------------------------------
__global__ __launch_bounds__(256, 4) void attn_mfma_kernel(
    const ushort* __restrict__ Qb, const ushort* __restrict__ Sb,
    const int* __restrict__ labels, float* __restrict__ partial,
    int nq, int ns_part, int D) {
  __shared__ ushort stile[16 * 512];   // 16 KB staged S chunk
  __shared__ float buckets[64][65];
  __shared__ int lab[64];
  const int tid = threadIdx.x;
  const int wave = tid >> 6, lane = tid & 63;
  const int fr = lane & 15, kg = lane >> 4;
  const long q0 = (long)blockIdx.x * 64;
  const int part = blockIdx.y;
  const long s_begin = (long)part * ns_part;

  for (int i = tid; i < 64 * 65; i += 256) ((float*)buckets)[i] = 0.0f;

  // Q-hoist: wave owns queries [q0 + wave*16, +16); 16 K-steps of bf16x8
  bf16x8 qf[16];
  const ushort* qrow = Qb + (q0 + wave * 16 + fr) * (size_t)D;
#pragma unroll
  for (int t = 0; t < 16; t++)
    qf[t] = *(const bf16x8*)(qrow + t * 32 + kg * 8);

  for (int st = 0; st < ns_part; st += 64) {
    const long s0 = s_begin + st;
    __syncthreads();               // prev-iter atomics done before lab overwrite
    if (tid < 64) lab[tid] = labels[s0 + tid];
    f32x4 acc[4];
#pragma unroll
    for (int c = 0; c < 4; c++) acc[c] = (f32x4){0.f, 0.f, 0.f, 0.f};

    for (int kc = 0; kc < 4; kc++) {   // 4 chunks of BK=128 over K=512
      // stage: each wave issues 4 independent global_load_lds (16B/lane)
#pragma unroll
      for (int i = 0; i < 4; i++) {
        const int btc = i * 4 + wave;          // wave-uniform block id
        const int tt = btc >> 2, cc = btc & 3;
        const ushort* src =
            Sb + (s0 + cc * 16 + fr) * (size_t)D + kc * 128 + tt * 32 + kg * 8;
        __builtin_amdgcn_global_load_lds(
            (const __attribute__((address_space(1))) void*)src,
            (__attribute__((address_space(3))) void*)&stile[btc * 512],
            16, 0, 0);
      }
      __syncthreads();   // drain vmcnt -> tile ready (also makes lab visible)
#pragma unroll
      for (int tt = 0; tt < 4; tt++) {
#pragma unroll
        for (int cc = 0; cc < 4; cc++) {
          bf16x8 bfr = *(const bf16x8*)&stile[(tt * 4 + cc) * 512 + lane * 8];
          acc[cc] = __builtin_amdgcn_mfma_f32_16x16x32_bf16(
              qf[kc * 4 + tt], bfr, acc[cc], 0, 0, 0);
        }
      }
      __syncthreads();   // ds_reads done before next chunk overwrites stile
    }
    // exp + bucket: lane's acc[c][r] = score(q0+wave*16+kg*4+r, s0+c*16+fr)
#pragma unroll
    for (int c = 0; c < 4; c++) {
      int lb = lab[c * 16 + fr];
#pragma unroll
      for (int r = 0; r < 4; r++) {
        float e = __expf(acc[c][r]);
        atomicAdd(&buckets[wave * 16 + kg * 4 + r][lb], e);
      }
    }
  }
  __syncthreads();
  for (int i = tid; i < 64 * 64; i += 256) {
    int q = i >> 6, c = i & 63;
    partial[((size_t)part * nq + (q0 + q)) * 64 + c] = buckets[q][c];
  }
}

// ---------------------------------------------------------------------------
// Combine: sum partials over splits; denominator = row-sum of buckets
// ---------------------------------------------------------------------------
__global__ __launch_bounds__(256) void combine_kernel(
    const float* __restrict__ partial, float* __restrict__ out, int nq, int nsplit) {
  int q = (int)((blockIdx.x * blockDim.x + threadIdx.x) >> 6);
  int lane = threadIdx.x & 63;
  if (q >= nq) return;
  float v = 0.0f;
  for (int h = 0; h < nsplit; h++)
    v += partial[((size_t)h * nq + q) * 64 + lane];
  float s = v;
#pragma unroll
  for (int off = 32; off > 0; off >>= 1) s += __shfl_xor(s, off);
  out[(size_t)q * 64 + lane] = v / s;
}

// ---------------------------------------------------------------------------
// Workspace layout (same proven scheme as round 5; all regions rewritten in
// order every call, aliases only reuse dead buffers):
//  [0,24M)  xb_s(8M)+xb_q(16M)  -> later aliased by s_bf[0,4M)+q_bf[4M,12M)
//  [12M,28M) partial (SPLIT=8)  -> aliases Wt/s_emb (dead by attn time)
//  [24M,25M) Wt  [25M,33M) s_emb  [33M,49M) q_emb
// ---------------------------------------------------------------------------
extern "C" void kernel_launch(void* const* d_in, const int* in_sizes, int n_in,
                              void* d_out, int out_size, void* d_ws, size_t ws_size,
                              hipStream_t stream) {
  const float* support = (const float*)d_in[0];
  const float* query   = (const float*)d_in[1];
  const float* W       = (const float*)d_in[2];
  const float* b       = (const float*)d_in[3];
  const int*   labels  = (const int*)d_in[4];

  const int d_dim    = in_sizes[3];            // 512
  const int in_dim   = in_sizes[2] / d_dim;    // 1024
  const int n_support = in_sizes[0] / in_dim;  // 4096
  const int n_query   = in_sizes[1] / in_dim;  // 8192

  char* base = (char*)d_ws;
  ushort* xb_s  = (ushort*)(base);
  ushort* xb_q  = (ushort*)(base + ((size_t)8 << 20));
  ushort* Wt    = (ushort*)(base + ((size_t)24 << 20));
  float*  s_emb = (float*)(base + ((size_t)25 << 20));
  float*  q_emb = (float*)(base + ((size_t)33 << 20));
  ushort* s_bf  = (ushort*)(base);                        // alias xb_s (dead)
  ushort* q_bf  = (ushort*)(base + ((size_t)4 << 20));    // alias xb (dead)
  float*  partial = (float*)(base + ((size_t)12 << 20));  // alias xb/Wt/s_emb (dead)

  dim3 blk(256);
  cast_bf16_kernel<<<2048, blk, 0, stream>>>(support, xb_s, (size_t)n_support * in_dim / 4);
  cast_bf16_kernel<<<2048, blk, 0, stream>>>(query, xb_q, (size_t)n_query * in_dim / 4);
  transpose_cast_kernel<<<dim3(in_dim / 64, d_dim / 64), blk, 0, stream>>>(W, Wt, in_dim, d_dim);
  encode_mfma_kernel<<<dim3(n_support / 64, d_dim / 64), blk, 0, stream>>>(
      xb_s, Wt, b, s_emb, in_dim, d_dim);
  encode_mfma_kernel<<<dim3(n_query / 64, d_dim / 64), blk, 0, stream>>>(
      xb_q, Wt, b, q_emb, in_dim, d_dim);
  norm_bf16_kernel<<<dim3(n_support / 4), blk, 0, stream>>>(s_emb, s_bf, n_support, d_dim);
  norm_bf16_kernel<<<dim3(n_query / 4), blk, 0, stream>>>(q_emb, q_bf, n_query, d_dim);
  attn_mfma_kernel<<<dim3(n_query / 64, SPLIT), blk, 0, stream>>>(
      q_bf, s_bf, labels, partial, n_query, n_support / SPLIT, d_dim);
  combine_kernel<<<dim3(n_query / 4), blk, 0, stream>>>(partial, (float*)d_out, n_query, SPLIT);
}

// Round 7
// 363.984 us; speedup vs baseline: 2.4024x; 1.0056x over previous
//
#include <hip/hip_runtime.h>
#include <hip/hip_bf16.h>
#include <math.h>

#define NPART 16  // s-blocks of 256: 64x16 = 1024 blocks = 2/CU (LDS-capped)

typedef __attribute__((ext_vector_type(8))) short bf16x8;  // MFMA A/B frag (4 VGPR)
typedef __attribute__((ext_vector_type(4))) float f32x4;   // MFMA C/D frag

static __device__ inline ushort f2bf(float x) {
  __hip_bfloat16 h = __float2bfloat16(x);
  return *reinterpret_cast<ushort*>(&h);
}

// ---------------------------------------------------------------------------
// Elementwise cast f32 -> bf16 (n multiple of 4)
// ---------------------------------------------------------------------------
__global__ __launch_bounds__(256) void cast_bf16_kernel(
    const float* __restrict__ in, ushort* __restrict__ out, size_t n4) {
  size_t i = (size_t)blockIdx.x * blockDim.x + threadIdx.x;
  size_t stride = (size_t)gridDim.x * blockDim.x;
  for (; i < n4; i += stride) {
    float4 v = ((const float4*)in)[i];
    ushort4 u;
    u.x = f2bf(v.x); u.y = f2bf(v.y); u.z = f2bf(v.z); u.w = f2bf(v.w);
    ((ushort4*)out)[i] = u;
  }
}

// ---------------------------------------------------------------------------
// Transpose-cast W[K][D] f32 -> Wt[D][K] bf16 (64x64 LDS tiles)
// ---------------------------------------------------------------------------
__global__ __launch_bounds__(256) void transpose_cast_kernel(
    const float* __restrict__ W, ushort* __restrict__ Wt, int K, int D) {
  __shared__ float t[64][65];
  const int k0 = blockIdx.x * 64, d0 = blockIdx.y * 64;
  const int r = threadIdx.x >> 6, c = threadIdx.x & 63;
#pragma unroll
  for (int i = 0; i < 16; i++)
    t[r + i * 4][c] = W[(size_t)(k0 + r + i * 4) * D + d0 + c];
  __syncthreads();
#pragma unroll
  for (int i = 0; i < 16; i++)
    Wt[(size_t)(d0 + r + i * 4) * K + k0 + c] = f2bf(t[c][r + i * 4]);
}

// ---------------------------------------------------------------------------
// Encoder MFMA GEMM (unchanged this round): emb = Xb @ Wt^T + b
// ---------------------------------------------------------------------------
__global__ __launch_bounds__(256) void encode_mfma_kernel(
    const ushort* __restrict__ Xb, const ushort* __restrict__ Wt,
    const float* __restrict__ bias, float* __restrict__ emb,
    int K, int D) {
  const int tid = threadIdx.x;
  const int wave = tid >> 6, lane = tid & 63;
  const int fr = lane & 15, kg = lane >> 4;
  const long row0 = (long)blockIdx.x * 64, col0 = (long)blockIdx.y * 64;

  f32x4 acc[4];
#pragma unroll
  for (int c = 0; c < 4; c++) acc[c] = (f32x4){0.f, 0.f, 0.f, 0.f};

  const ushort* xrow = Xb + (row0 + wave * 16 + fr) * (size_t)K;
  const int nt = K / 32;
  for (int t = 0; t < nt; t++) {
    bf16x8 af = *(const bf16x8*)(xrow + t * 32 + kg * 8);
#pragma unroll
    for (int c = 0; c < 4; c++) {
      const ushort* wrow = Wt + (col0 + c * 16 + fr) * (size_t)K;
      bf16x8 bf = *(const bf16x8*)(wrow + t * 32 + kg * 8);
      acc[c] = __builtin_amdgcn_mfma_f32_16x16x32_bf16(af, bf, acc[c], 0, 0, 0);
    }
  }
#pragma unroll
  for (int c = 0; c < 4; c++) {
    float bl = bias[col0 + c * 16 + fr];
#pragma unroll
    for (int r = 0; r < 4; r++)
      emb[(row0 + wave * 16 + kg * 4 + r) * (size_t)D + col0 + c * 16 + fr] =
          acc[c][r] + bl;
  }
}

// ---------------------------------------------------------------------------
// Row L2-normalize fp32 -> bf16 (one wave per row, D = 512)
// ---------------------------------------------------------------------------
__global__ __launch_bounds__(256) void norm_bf16_kernel(
    const float* __restrict__ in, ushort* __restrict__ outb, int nrows, int D) {
  int row = (int)((blockIdx.x * blockDim.x + threadIdx.x) >> 6);
  int lane = threadIdx.x & 63;
  if (row >= nrows) return;
  const float4* p = (const float4*)(in + (size_t)row * D);
  float4 v0 = p[lane];
  float4 v1 = p[lane + 64];
  float ss = v0.x * v0.x + v0.y * v0.y + v0.z * v0.z + v0.w * v0.w
           + v1.x * v1.x + v1.y * v1.y + v1.z * v1.z + v1.w * v1.w;
#pragma unroll
  for (int off = 32; off > 0; off >>= 1) ss += __shfl_xor(ss, off);
  float inv = 1.0f / fmaxf(sqrtf(ss), 1e-12f);
  ushort4 u0, u1;
  u0.x = f2bf(v0.x * inv); u0.y = f2bf(v0.y * inv);
  u0.z = f2bf(v0.z * inv); u0.w = f2bf(v0.w * inv);
  u1.x = f2bf(v1.x * inv); u1.y = f2bf(v1.y * inv);
  u1.z = f2bf(v1.z * inv); u1.w = f2bf(v1.w * inv);
  ushort* o = outb + (size_t)row * D;
  *(ushort4*)(o + 4 * lane) = u0;
  *(ushort4*)(o + 256 + 4 * lane) = u1;
}

// ---------------------------------------------------------------------------
// MFMA attention, m97-shaped: 512 threads (8 waves, 2x4), block tile
// 128q x 256s, wave tile 64q x 64s (acc[4][4] f32x4). BK=32 per step:
// stage 24 x 1KB fragment-order segments (8 Q row-groups + 16 S col-groups)
// via global_load_lds (linear LDS dest, pre-permuted global src — proven
// round 6), 2-barrier loop, 16 MFMA per 8 ds_read per wave per step.
// Then exp + LDS-atomic 64-class buckets (scores in [-1,1], no max needed).
// ---------------------------------------------------------------------------
__global__ __launch_bounds__(512, 4) void attn_mfma_kernel(
    const ushort* __restrict__ Qb, const ushort* __restrict__ Sb,
    const int* __restrict__ labels, float* __restrict__ partial,
    int nq, int D) {
  __shared__ ushort tile[24 * 512];    // 24 KB: segs 0-7 = Q, 8-23 = S
  __shared__ float buckets[128][65];   // 33.25 KB
  __shared__ int lab[256];
  const int tid = threadIdx.x;
  const int wave = tid >> 6, lane = tid & 63;
  const int fr = lane & 15, kg = lane >> 4;
  const int wr = wave >> 2, wc = wave & 3;   // 2x4 wave grid
  const long q0 = (long)blockIdx.x * 128;
  const int part = blockIdx.y;
  const long s0 = (long)part * 256;

  for (int i = tid; i < 128 * 65; i += 512) ((float*)buckets)[i] = 0.0f;
  if (tid < 256) lab[tid] = labels[s0 + tid];

  f32x4 acc[4][4];
#pragma unroll
  for (int rg = 0; rg < 4; rg++)
#pragma unroll
    for (int cg = 0; cg < 4; cg++) acc[rg][cg] = (f32x4){0.f, 0.f, 0.f, 0.f};

  for (int kk = 0; kk < 16; kk++) {    // K = 512 = 16 x BK(32)
    // stage: 3 segments per wave, 16B/lane, fragment-order global source
#pragma unroll
    for (int i = 0; i < 3; i++) {
      const int seg = wave * 3 + i;
      const ushort* src = (seg < 8)
          ? Qb + (q0 + seg * 16 + fr) * (size_t)D + kk * 32 + kg * 8
          : Sb + (s0 + (seg - 8) * 16 + fr) * (size_t)D + kk * 32 + kg * 8;
      __builtin_amdgcn_global_load_lds(
          (const __attribute__((address_space(1))) void*)src,
          (__attribute__((address_space(3))) void*)&tile[seg * 512],
          16, 0, 0);
    }
    __syncthreads();                   // tile ready (covers lab on kk=0)
    bf16x8 bfr[4];
#pragma unroll
    for (int cg = 0; cg < 4; cg++)
      bfr[cg] = *(const bf16x8*)&tile[(8 + wc * 4 + cg) * 512 + lane * 8];
#pragma unroll
    for (int rg = 0; rg < 4; rg++) {
      bf16x8 af = *(const bf16x8*)&tile[(wr * 4 + rg) * 512 + lane * 8];
#pragma unroll
      for (int cg = 0; cg < 4; cg++)
        acc[rg][cg] = __builtin_amdgcn_mfma_f32_16x16x32_bf16(
            af, bfr[cg], acc[rg][cg], 0, 0, 0);
    }
    __syncthreads();                   // reads done before next overwrite
  }
  // exp + bucket: acc[rg][cg][r] = score(q0+wr*64+rg*16+kg*4+r,
  //                                      s0+wc*64+cg*16+fr)
#pragma unroll
  for (int cg = 0; cg < 4; cg++) {
    int lb = lab[wc * 64 + cg * 16 + fr];
#pragma unroll
    for (int rg = 0; rg < 4; rg++)
#pragma unroll
      for (int r = 0; r < 4; r++)
        atomicAdd(&buckets[wr * 64 + rg * 16 + kg * 4 + r][lb],
                  __expf(acc[rg][cg][r]));
  }
  __syncthreads();
  for (int i = tid; i < 128 * 64; i += 512) {
    int q = i >> 6, c = i & 63;
    partial[((size_t)part * nq + (q0 + q)) * 64 + c] = buckets[q][c];
  }
}

// ---------------------------------------------------------------------------
// Combine: sum partials over splits; denominator = row-sum of buckets
// ---------------------------------------------------------------------------
__global__ __launch_bounds__(256) void combine_kernel(
    const float* __restrict__ partial, float* __restrict__ out, int nq, int nsplit) {
  int q = (int)((blockIdx.x * blockDim.x + threadIdx.x) >> 6);
  int lane = threadIdx.x & 63;
  if (q >= nq) return;
  float v = 0.0f;
  for (int h = 0; h < nsplit; h++)
    v += partial[((size_t)h * nq + q) * 64 + lane];
  float s = v;
#pragma unroll
  for (int off = 32; off > 0; off >>= 1) s += __shfl_xor(s, off);
  out[(size_t)q * 64 + lane] = v / s;
}

// ---------------------------------------------------------------------------
// Workspace layout (peak 49 MB; aliases only reuse dead buffers):
//  [0,8M) xb_s  [8M,24M) xb_q  [24M,25M) Wt  [25M,33M) s_emb  [33M,49M) q_emb
//  after encode+norm: s_bf [0,4M), q_bf [4M,12M), partial [12M,44M) (32 MB)
// ---------------------------------------------------------------------------
extern "C" void kernel_launch(void* const* d_in, const int* in_sizes, int n_in,
                              void* d_out, int out_size, void* d_ws, size_t ws_size,
                              hipStream_t stream) {
  const float* support = (const float*)d_in[0];
  const float* query   = (const float*)d_in[1];
  const float* W       = (const float*)d_in[2];
  const float* b       = (const float*)d_in[3];
  const int*   labels  = (const int*)d_in[4];

  const int d_dim    = in_sizes[3];            // 512
  const int in_dim   = in_sizes[2] / d_dim;    // 1024
  const int n_support = in_sizes[0] / in_dim;  // 4096
  const int n_query   = in_sizes[1] / in_dim;  // 8192

  char* base = (char*)d_ws;
  ushort* xb_s  = (ushort*)(base);
  ushort* xb_q  = (ushort*)(base + ((size_t)8 << 20));
  ushort* Wt    = (ushort*)(base + ((size_t)24 << 20));
  float*  s_emb = (float*)(base + ((size_t)25 << 20));
  float*  q_emb = (float*)(base + ((size_t)33 << 20));
  ushort* s_bf  = (ushort*)(base);                        // alias xb_s (dead)
  ushort* q_bf  = (ushort*)(base + ((size_t)4 << 20));    // alias xb (dead)
  float*  partial = (float*)(base + ((size_t)12 << 20));  // alias xb/Wt/emb (dead)

  dim3 blk(256);
  cast_bf16_kernel<<<2048, blk, 0, stream>>>(support, xb_s, (size_t)n_support * in_dim / 4);
  cast_bf16_kernel<<<2048, blk, 0, stream>>>(query, xb_q, (size_t)n_query * in_dim / 4);
  transpose_cast_kernel<<<dim3(in_dim / 64, d_dim / 64), blk, 0, stream>>>(W, Wt, in_dim, d_dim);
  encode_mfma_kernel<<<dim3(n_support / 64, d_dim / 64), blk, 0, stream>>>(
      xb_s, Wt, b, s_emb, in_dim, d_dim);
  encode_mfma_kernel<<<dim3(n_query / 64, d_dim / 64), blk, 0, stream>>>(
      xb_q, Wt, b, q_emb, in_dim, d_dim);
  norm_bf16_kernel<<<dim3(n_support / 4), blk, 0, stream>>>(s_emb, s_bf, n_support, d_dim);
  norm_bf16_kernel<<<dim3(n_query / 4), blk, 0, stream>>>(q_emb, q_bf, n_query, d_dim);
  attn_mfma_kernel<<<dim3(n_query / 128, NPART), dim3(512), 0, stream>>>(
      q_bf, s_bf, labels, partial, n_query, d_dim);
  combine_kernel<<<dim3(n_query / 4), blk, 0, stream>>>(partial, (float*)d_out, n_query, NPART);
}

// Round 9
// 349.386 us; speedup vs baseline: 2.5027x; 1.0418x over previous
//
#include <hip/hip_runtime.h>
#include <hip/hip_bf16.h>
#include <math.h>

#define NPART 16  // s-blocks of 256: 64x16 = 1024 blocks

typedef __attribute__((ext_vector_type(8))) short bf16x8;  // MFMA A/B frag (4 VGPR)
typedef __attribute__((ext_vector_type(4))) float f32x4;   // MFMA C/D frag

static __device__ inline ushort f2bf(float x) {
  __hip_bfloat16 h = __float2bfloat16(x);
  return *reinterpret_cast<ushort*>(&h);
}

// ---------------------------------------------------------------------------
// Elementwise cast f32 -> bf16 (n multiple of 4)
// ---------------------------------------------------------------------------
__global__ __launch_bounds__(256) void cast_bf16_kernel(
    const float* __restrict__ in, ushort* __restrict__ out, size_t n4) {
  size_t i = (size_t)blockIdx.x * blockDim.x + threadIdx.x;
  size_t stride = (size_t)gridDim.x * blockDim.x;
  for (; i < n4; i += stride) {
    float4 v = ((const float4*)in)[i];
    ushort4 u;
    u.x = f2bf(v.x); u.y = f2bf(v.y); u.z = f2bf(v.z); u.w = f2bf(v.w);
    ((ushort4*)out)[i] = u;
  }
}

// ---------------------------------------------------------------------------
// Transpose-cast W[K][D] f32 -> Wt[D][K] bf16 (64x64 LDS tiles)
// ---------------------------------------------------------------------------
__global__ __launch_bounds__(256) void transpose_cast_kernel(
    const float* __restrict__ W, ushort* __restrict__ Wt, int K, int D) {
  __shared__ float t[64][65];
  const int k0 = blockIdx.x * 64, d0 = blockIdx.y * 64;
  const int r = threadIdx.x >> 6, c = threadIdx.x & 63;
#pragma unroll
  for (int i = 0; i < 16; i++)
    t[r + i * 4][c] = W[(size_t)(k0 + r + i * 4) * D + d0 + c];
  __syncthreads();
#pragma unroll
  for (int i = 0; i < 16; i++)
    Wt[(size_t)(d0 + r + i * 4) * K + k0 + c] = f2bf(t[c][r + i * 4]);
}

// ---------------------------------------------------------------------------
// Encoder MFMA GEMM (unchanged this round): emb = Xb @ Wt^T + b
// ---------------------------------------------------------------------------
__global__ __launch_bounds__(256) void encode_mfma_kernel(
    const ushort* __restrict__ Xb, const ushort* __restrict__ Wt,
    const float* __restrict__ bias, float* __restrict__ emb,
    int K, int D) {
  const int tid = threadIdx.x;
  const int wave = tid >> 6, lane = tid & 63;
  const int fr = lane & 15, kg = lane >> 4;
  const long row0 = (long)blockIdx.x * 64, col0 = (long)blockIdx.y * 64;

  f32x4 acc[4];
#pragma unroll
  for (int c = 0; c < 4; c++) acc[c] = (f32x4){0.f, 0.f, 0.f, 0.f};

  const ushort* xrow = Xb + (row0 + wave * 16 + fr) * (size_t)K;
  const int nt = K / 32;
  for (int t = 0; t < nt; t++) {
    bf16x8 af = *(const bf16x8*)(xrow + t * 32 + kg * 8);
#pragma unroll
    for (int c = 0; c < 4; c++) {
      const ushort* wrow = Wt + (col0 + c * 16 + fr) * (size_t)K;
      bf16x8 bf = *(const bf16x8*)(wrow + t * 32 + kg * 8);
      acc[c] = __builtin_amdgcn_mfma_f32_16x16x32_bf16(af, bf, acc[c], 0, 0, 0);
    }
  }
#pragma unroll
  for (int c = 0; c < 4; c++) {
    float bl = bias[col0 + c * 16 + fr];
#pragma unroll
    for (int r = 0; r < 4; r++)
      emb[(row0 + wave * 16 + kg * 4 + r) * (size_t)D + col0 + c * 16 + fr] =
          acc[c][r] + bl;
  }
}

// ---------------------------------------------------------------------------
// Row L2-normalize fp32 -> bf16 (one wave per row, D = 512)
// ---------------------------------------------------------------------------
__global__ __launch_bounds__(256) void norm_bf16_kernel(
    const float* __restrict__ in, ushort* __restrict__ outb, int nrows, int D) {
  int row = (int)((blockIdx.x * blockDim.x + threadIdx.x) >> 6);
  int lane = threadIdx.x & 63;
  if (row >= nrows) return;
  const float4* p = (const float4*)(in + (size_t)row * D);
  float4 v0 = p[lane];
  float4 v1 = p[lane + 64];
  float ss = v0.x * v0.x + v0.y * v0.y + v0.z * v0.z + v0.w * v0.w
           + v1.x * v1.x + v1.y * v1.y + v1.z * v1.z + v1.w * v1.w;
#pragma unroll
  for (int off = 32; off > 0; off >>= 1) ss += __shfl_xor(ss, off);
  float inv = 1.0f / fmaxf(sqrtf(ss), 1e-12f);
  ushort4 u0, u1;
  u0.x = f2bf(v0.x * inv); u0.y = f2bf(v0.y * inv);
  u0.z = f2bf(v0.z * inv); u0.w = f2bf(v0.w * inv);
  u1.x = f2bf(v1.x * inv); u1.y = f2bf(v1.y * inv);
  u1.z = f2bf(v1.z * inv); u1.w = f2bf(v1.w * inv);
  ushort* o = outb + (size_t)row * D;
  *(ushort4*)(o + 4 * lane) = u0;
  *(ushort4*)(o + 256 + 4 * lane) = u1;
}

// ---------------------------------------------------------------------------
// MFMA attention, r7 structure with LANE-LINEAR staging (H2 fix):
// 512 threads (8 waves, 2x4), block tile 128q x 256s, wave 64q x 64s, BK=32.
// Stage Qs[128][32] @ ushort 0 and Ss[256][32] @ ushort 4096, row-major, via
// global_load_lds whose per-lane global source is lane-linear (lane l ->
// row base+(l>>2), byte (l&3)*16): 4-lane 64B contiguous runs -> proper
// VMEM coalescing. Fragment reads address the row-major tile: each wave's
// 64 lanes read 64 distinct 16B chunks of a contiguous 1KB block (chunk
// idx fr*4+kg bijective). Math bit-identical to round 7.
// (r8 bug fixed: S read base was 8192 ushorts — comment meant BYTES; the
//  staged S base is ushort 4096. Near-uniform attention masked it to 6e-4.)
// ---------------------------------------------------------------------------
__global__ __launch_bounds__(512, 4) void attn_mfma_kernel(
    const ushort* __restrict__ Qb, const ushort* __restrict__ Sb,
    const int* __restrict__ labels, float* __restrict__ partial,
    int nq, int D) {
  __shared__ ushort tile[24 * 512];    // Qs[128][32] @ 0, Ss[256][32] @ 4096
  __shared__ float buckets[128][65];   // 33.25 KB
  __shared__ int lab[256];
  const int tid = threadIdx.x;
  const int wave = tid >> 6, lane = tid & 63;
  const int fr = lane & 15, kg = lane >> 4;
  const int wr = wave >> 2, wc = wave & 3;   // 2x4 wave grid
  const int lrow = lane >> 2;                // staging: row within 16-row seg
  const int lcol = (lane & 3) * 8;           // staging: ushort col offset
  const long q0 = (long)blockIdx.x * 128;
  const int part = blockIdx.y;
  const long s0 = (long)part * 256;

  for (int i = tid; i < 128 * 65; i += 512) ((float*)buckets)[i] = 0.0f;
  if (tid < 256) lab[tid] = labels[s0 + tid];

  f32x4 acc[4][4];
#pragma unroll
  for (int rg = 0; rg < 4; rg++)
#pragma unroll
    for (int cg = 0; cg < 4; cg++) acc[rg][cg] = (f32x4){0.f, 0.f, 0.f, 0.f};

  for (int kk = 0; kk < 16; kk++) {    // K = 512 = 16 x BK(32)
    // stage: 3 segs/wave; seg<8 = Q rows, seg>=8 = S rows; lane-linear src
#pragma unroll
    for (int i = 0; i < 3; i++) {
      const int seg = wave * 3 + i;
      const ushort* src = (seg < 8)
          ? Qb + (q0 + seg * 16 + lrow) * (size_t)D + kk * 32 + lcol
          : Sb + (s0 + (seg - 8) * 16 + lrow) * (size_t)D + kk * 32 + lcol;
      __builtin_amdgcn_global_load_lds(
          (const __attribute__((address_space(1))) void*)src,
          (__attribute__((address_space(3))) void*)&tile[seg * 512],
          16, 0, 0);
    }
    __syncthreads();                   // tile ready (covers lab/buckets on kk=0)
    bf16x8 bfr[4];
#pragma unroll
    for (int cg = 0; cg < 4; cg++)
      bfr[cg] = *(const bf16x8*)&tile[4096 + (wc * 64 + cg * 16 + fr) * 32 + kg * 8];
#pragma unroll
    for (int rg = 0; rg < 4; rg++) {
      bf16x8 af = *(const bf16x8*)&tile[(wr * 64 + rg * 16 + fr) * 32 + kg * 8];
#pragma unroll
      for (int cg = 0; cg < 4; cg++)
        acc[rg][cg] = __builtin_amdgcn_mfma_f32_16x16x32_bf16(
            af, bfr[cg], acc[rg][cg], 0, 0, 0);
    }
    __syncthreads();                   // reads done before next overwrite
  }
  // exp + bucket: acc[rg][cg][r] = score(q0+wr*64+rg*16+kg*4+r,
  //                                      s0+wc*64+cg*16+fr)
#pragma unroll
  for (int cg = 0; cg < 4; cg++) {
    int lb = lab[wc * 64 + cg * 16 + fr];
#pragma unroll
    for (int rg = 0; rg < 4; rg++)
#pragma unroll
      for (int r = 0; r < 4; r++)
        atomicAdd(&buckets[wr * 64 + rg * 16 + kg * 4 + r][lb],
                  __expf(acc[rg][cg][r]));
  }
  __syncthreads();
  for (int i = tid; i < 128 * 64; i += 512) {
    int q = i >> 6, c = i & 63;
    partial[((size_t)part * nq + (q0 + q)) * 64 + c] = buckets[q][c];
  }
}

// ---------------------------------------------------------------------------
// Combine: sum partials over splits; denominator = row-sum of buckets
// ---------------------------------------------------------------------------
__global__ __launch_bounds__(256) void combine_kernel(
    const float* __restrict__ partial, float* __restrict__ out, int nq, int nsplit) {
  int q = (int)((blockIdx.x * blockDim.x + threadIdx.x) >> 6);
  int lane = threadIdx.x & 63;
  if (q >= nq) return;
  float v = 0.0f;
  for (int h = 0; h < nsplit; h++)
    v += partial[((size_t)h * nq + q) * 64 + lane];
  float s = v;
#pragma unroll
  for (int off = 32; off > 0; off >>= 1) s += __shfl_xor(s, off);
  out[(size_t)q * 64 + lane] = v / s;
}

// ---------------------------------------------------------------------------
// Workspace layout (peak 49 MB; aliases only reuse dead buffers):
//  [0,8M) xb_s  [8M,24M) xb_q  [24M,25M) Wt  [25M,33M) s_emb  [33M,49M) q_emb
//  after encode+norm: s_bf [0,4M), q_bf [4M,12M), partial [12M,44M) (32 MB)
// ---------------------------------------------------------------------------
extern "C" void kernel_launch(void* const* d_in, const int* in_sizes, int n_in,
                              void* d_out, int out_size, void* d_ws, size_t ws_size,
                              hipStream_t stream) {
  const float* support = (const float*)d_in[0];
  const float* query   = (const float*)d_in[1];
  const float* W       = (const float*)d_in[2];
  const float* b       = (const float*)d_in[3];
  const int*   labels  = (const int*)d_in[4];

  const int d_dim    = in_sizes[3];            // 512
  const int in_dim   = in_sizes[2] / d_dim;    // 1024
  const int n_support = in_sizes[0] / in_dim;  // 4096
  const int n_query   = in_sizes[1] / in_dim;  // 8192

  char* base = (char*)d_ws;
  ushort* xb_s  = (ushort*)(base);
  ushort* xb_q  = (ushort*)(base + ((size_t)8 << 20));
  ushort* Wt    = (ushort*)(base + ((size_t)24 << 20));
  float*  s_emb = (float*)(base + ((size_t)25 << 20));
  float*  q_emb = (float*)(base + ((size_t)33 << 20));
  ushort* s_bf  = (ushort*)(base);                        // alias xb_s (dead)
  ushort* q_bf  = (ushort*)(base + ((size_t)4 << 20));    // alias xb (dead)
  float*  partial = (float*)(base + ((size_t)12 << 20));  // alias xb/Wt/emb (dead)

  dim3 blk(256);
  cast_bf16_kernel<<<2048, blk, 0, stream>>>(support, xb_s, (size_t)n_support * in_dim / 4);
  cast_bf16_kernel<<<2048, blk, 0, stream>>>(query, xb_q, (size_t)n_query * in_dim / 4);
  transpose_cast_kernel<<<dim3(in_dim / 64, d_dim / 64), blk, 0, stream>>>(W, Wt, in_dim, d_dim);
  encode_mfma_kernel<<<dim3(n_support / 64, d_dim / 64), blk, 0, stream>>>(
      xb_s, Wt, b, s_emb, in_dim, d_dim);
  encode_mfma_kernel<<<dim3(n_query / 64, d_dim / 64), blk, 0, stream>>>(
      xb_q, Wt, b, q_emb, in_dim, d_dim);
  norm_bf16_kernel<<<dim3(n_support / 4), blk, 0, stream>>>(s_emb, s_bf, n_support, d_dim);
  norm_bf16_kernel<<<dim3(n_query / 4), blk, 0, stream>>>(q_emb, q_bf, n_query, d_dim);
  attn_mfma_kernel<<<dim3(n_query / 128, NPART), dim3(512), 0, stream>>>(
      q_bf, s_bf, labels, partial, n_query, d_dim);
  combine_kernel<<<dim3(n_query / 4), blk, 0, stream>>>(partial, (float*)d_out, n_query, NPART);
}